// Round 14
// baseline (427.554 us; speedup 1.0000x reference)
//
#include <hip/hip_runtime.h>
#include <hip/hip_fp16.h>

#define N_NODES 8192
#define DEG     16
#define NEDGE   (N_NODES*DEG)
#define F       128
#define F3      384
#define RBF     20
#define NLAYER  3
#define NF      (N_NODES*F)
#define PI_F    3.14159265358979f

typedef unsigned short u16;
typedef __bf16 bf16x8 __attribute__((ext_vector_type(8)));
typedef float  f32x4  __attribute__((ext_vector_type(4)));
typedef _Float16 f16x2 __attribute__((ext_vector_type(2)));

__device__ __forceinline__ float bf2f(u16 u){ return __uint_as_float(((unsigned)u)<<16); }
__device__ __forceinline__ u16 f2bf(float f){
  unsigned x = __float_as_uint(f);
  unsigned r = (x + 0x7FFFu + ((x>>16)&1u)) >> 16;   // RNE
  return (u16)r;
}
__device__ __forceinline__ float lo_bf(unsigned u){ return __uint_as_float(u<<16); }
__device__ __forceinline__ float hi_bf(unsigned u){ return __uint_as_float(u & 0xFFFF0000u); }
__device__ __forceinline__ float silu_f(float x){ return x / (1.f + __expf(-x)); }
__device__ __forceinline__ float ldsrc(const void* src, int i, int bf){
  return bf ? bf2f(((const u16*)src)[i]) : ((const float*)src)[i];
}
__device__ __forceinline__ unsigned packh2(float a, float b){
  return (unsigned)__half_as_ushort(__float2half(a)) |
         ((unsigned)__half_as_ushort(__float2half(b)) << 16);
}
// v_dot2_f32_f16: c += a.x*b.x + a.y*b.y  (fp32 accumulate, 1 VALU op)
__device__ __forceinline__ float fdot2u(unsigned a, unsigned b, float c){
  return __builtin_amdgcn_fdot2(__builtin_bit_cast(f16x2, a),
                                __builtin_bit_cast(f16x2, b), c, false);
}

// ------------------------------------------------------------ dtype detect
__global__ void k_detect(const u16* __restrict__ rd, int* __restrict__ flag){
  if (threadIdx.x == 0 && blockIdx.x == 0){
    int ok = 1;
    for (int i = 0; i < 128; i++){
      float v = bf2f(rd[2*i]);
      if (!(v > 0.01f && v < 4.0f)) { ok = 0; break; }
    }
    *flag = ok;   // 1 = inputs bf16, 0 = fp32
  }
}

// ------------------------------------------- split helper: [L][K][N] -> [L][N][K] hi/lo
__device__ __forceinline__ void splitw(const void* src, u16* bh, u16* bl,
                                       int i, int K, int Ncol, int bf){
  int kn = K*Ncol; int l = i/kn; int r = i - l*kn; int k = r/Ncol; int n = r - k*Ncol;
  float w = ldsrc(src, i, bf);
  u16 h = f2bf(w);
  size_t o = (size_t)l*kn + (size_t)n*K + k;
  bh[o] = h; bl[o] = f2bf(w - bf2f(h));
}

// -------------------------------------- fused preamble (weights + edges + node init)
__global__ __launch_bounds__(256) void k_prep(
    const void* mb1, const void* mb2, const void* b1, const void* b2,
    const void* rw,  const void* rb,
    const void* mw1, const void* mw2, const void* w1, const void* w2,
    const void* Uw,  const void* Vw,
    const void* dist, const void* dirv, const int* __restrict__ idxj,
    const int* __restrict__ atoms, const void* __restrict__ emb,
    float* c_mb1, float* c_mb2, float* c_b1, float* c_b2,
    unsigned* rwp2,                 // [L][11][3F]
    u16* mw1h, u16* mw1l, u16* mw2h, u16* mw2l, u16* w1h, u16* w1l,
    u16* w2h, u16* w2l, u16* uvh, u16* uvl,
    uint4* edata,                   // [E][4]
    float* s, u16* s_h, u16* s_l,
    u16* p0h, u16* p0l, u16* bufA16, u16* bufB16,
    const int* __restrict__ flag){
  int i = blockIdx.x*256 + threadIdx.x;
  int bf = *flag;
  const int S0=NLAYER*F, S1=NLAYER*F3, S2=NLAYER*F, S3=NLAYER*F3;
  const int S4=NLAYER*11*F3;
  const int S5=NLAYER*F*F, S6=NLAYER*F*F3, S7=NLAYER*2*F*F, S8=NLAYER*F*F3, S9=NLAYER*256*F;
  if (i < S0){ c_mb1[i]=ldsrc(mb1,i,bf); return; } i-=S0;
  if (i < S1){ c_mb2[i]=ldsrc(mb2,i,bf); return; } i-=S1;
  if (i < S2){ c_b1[i] =ldsrc(b1, i,bf); return; } i-=S2;
  if (i < S3){ c_b2[i] =ldsrc(b2, i,bf); return; } i-=S3;
  if (i < S4){
    int l = i/(11*F3); int r = i - l*(11*F3); int r2 = r/F3; int col = r - r2*F3;
    float w0, w1v;
    if (r2 < 10){
      w0  = ldsrc(rw, (l*RBF + 2*r2  )*F3 + col, bf);
      w1v = ldsrc(rw, (l*RBF + 2*r2+1)*F3 + col, bf);
    } else {
      w0  = ldsrc(rb, l*F3 + col, bf);
      w1v = 0.f;
    }
    rwp2[i] = packh2(w0, w1v);
    return;
  } i-=S4;
  if (i < S5){ splitw(mw1, mw1h, mw1l, i, F,   F,  bf); return; } i-=S5;
  if (i < S6){ splitw(mw2, mw2h, mw2l, i, F,   F3, bf); return; } i-=S6;
  if (i < S7){ splitw(w1,  w1h,  w1l,  i, 2*F, F,  bf); return; } i-=S7;
  if (i < S8){ splitw(w2,  w2h,  w2l,  i, F,   F3, bf); return; } i-=S8;
  if (i < S9){
    int l=i/(256*F); int r=i-l*(256*F); int n=r>>7; int k=r&127;
    int si=(l*F+k)*F+(n&127);
    float w = ldsrc((n<128)?Uw:Vw, si, bf);
    u16 h=f2bf(w); uvh[i]=h; uvl[i]=f2bf(w-bf2f(h));
    return;
  } i-=S9;
  if (i < NEDGE){
    int e = i;
    float d = ldsrc(dist, e, bf);
    float th = PI_F*d*(1.f/3.f);
    float c  = __cosf(th);
    float s1 = __sinf(th);
    float cut = 0.5f*(c + 1.0f);
    float ic = cut/d;
    // Chebyshev recurrence: sin((k+1)th) = 2c*sin(k th) - sin((k-1) th)
    float sk[RBF+1];
    sk[0] = s1; float sm1 = 0.f, s0 = s1;
    #pragma unroll
    for (int k=1;k<=RBF;k++){ float sn = 2.f*c*s0 - sm1; sk[k-1] = s0; sm1 = s0; s0 = sn; }
    unsigned o[16];
    #pragma unroll
    for (int r2=0;r2<10;r2++)
      o[r2] = packh2(sk[2*r2]*ic, sk[2*r2+1]*ic);
    o[10] = packh2(cut, 0.f);
    o[11] = __float_as_uint(ldsrc(dirv, e*3+0, bf));
    o[12] = __float_as_uint(ldsrc(dirv, e*3+1, bf));
    o[13] = __float_as_uint(ldsrc(dirv, e*3+2, bf));
    o[14] = (unsigned)idxj[e];
    o[15] = 0;
    uint4* dst = edata + (size_t)e*4;
    dst[0] = make_uint4(o[0],o[1],o[2],o[3]);
    dst[1] = make_uint4(o[4],o[5],o[6],o[7]);
    dst[2] = make_uint4(o[8],o[9],o[10],o[11]);
    dst[3] = make_uint4(o[12],o[13],o[14],o[15]);
    return;
  } i-=NEDGE;
  if (i < NF){                      // node init
    int n = i >> 7, f = i & 127;
    float sv = ldsrc(emb, atoms[n]*F + f, bf);
    s[i] = sv;
    u16 hb = f2bf(sv); s_h[i] = hb; s_l[i] = f2bf(sv - bf2f(hb));
    p0h[i]=0; p0h[NF+i]=0; p0h[2*(size_t)NF+i]=0;
    p0l[i]=0; p0l[NF+i]=0; p0l[2*(size_t)NF+i]=0;
    bufA16[(size_t)i*4+2]=0; bufA16[(size_t)i*4+3]=0;
    bufB16[(size_t)i*2+1]=0;
  }
}
#define PREP_TOTAL (NLAYER*(F+F3+F+F3+11*F3+F*F+F*F3+2*F*F+F*F3+256*F) + NEDGE + NF)

// --------------------------------- fused message MLP: phi = silu(s@mw1+b1)@mw2+b2
__global__ __launch_bounds__(256) void k_msg(const u16* __restrict__ s_h,
                                             const u16* __restrict__ s_l,
                                             const u16* __restrict__ w1h_,  // [128][128]
                                             const u16* __restrict__ w1l_,
                                             const u16* __restrict__ w2h_,  // [384][128]
                                             const u16* __restrict__ w2l_,
                                             const float* __restrict__ b1,
                                             const float* __restrict__ b2,
                                             u16* __restrict__ bufA16,
                                             u16* __restrict__ bufB16){
  __shared__ u16 Ah[16*136], Al[16*136];
  __shared__ u16 Hh[16*136], Hl[16*136];
  __shared__ u16 Bh[64*136], Bl[64*136];
  int t = threadIdx.x, lane = t&63, w = t>>6;
  int row0 = blockIdx.x<<4;
  int l15 = lane&15, q8 = (lane>>4)<<3, qrow = (lane>>4)<<2;

  #pragma unroll
  for (int q=0;q<2;q++){
    int id = t + 256*q; int pl = id>>8, rem = id&255, r = rem>>4, c = (rem&15)<<3;
    *(uint4*)((pl?Al:Ah)+r*136+c) = *(const uint4*)((pl?s_l:s_h) + (size_t)(row0+r)*F + c);
  }

  for (int cg=0;cg<2;cg++){
    __syncthreads();
    #pragma unroll
    for (int q=0;q<8;q++){
      int id = t + 256*q; int pl = id>>10, rem = id&1023, r = rem>>4, c = (rem&15)<<3;
      *(uint4*)((pl?Bl:Bh)+r*136+c) = *(const uint4*)((pl?w1l_:w1h_) + (size_t)(cg*64+r)*F + c);
    }
    __syncthreads();
    f32x4 acc; acc[0]=0;acc[1]=0;acc[2]=0;acc[3]=0;
    #pragma unroll
    for (int k0=0;k0<F;k0+=32){
      bf16x8 a_h = *(const bf16x8*)&Ah[l15*136 + k0 + q8];
      bf16x8 a_l = *(const bf16x8*)&Al[l15*136 + k0 + q8];
      bf16x8 b_h = *(const bf16x8*)&Bh[(w*16+l15)*136 + k0 + q8];
      bf16x8 b_l = *(const bf16x8*)&Bl[(w*16+l15)*136 + k0 + q8];
      acc = __builtin_amdgcn_mfma_f32_16x16x32_bf16(a_h, b_h, acc, 0,0,0);
      acc = __builtin_amdgcn_mfma_f32_16x16x32_bf16(a_h, b_l, acc, 0,0,0);
      acc = __builtin_amdgcn_mfma_f32_16x16x32_bf16(a_l, b_h, acc, 0,0,0);
    }
    int col = cg*64 + w*16 + l15;
    float bb = b1[col];
    #pragma unroll
    for (int r=0;r<4;r++){
      float val = silu_f(acc[r] + bb);
      u16 hb = f2bf(val);
      Hh[(qrow+r)*136 + col] = hb;
      Hl[(qrow+r)*136 + col] = f2bf(val - bf2f(hb));
    }
  }

  for (int cg=0;cg<6;cg++){
    __syncthreads();
    #pragma unroll
    for (int q=0;q<8;q++){
      int id = t + 256*q; int pl = id>>10, rem = id&1023, r = rem>>4, c = (rem&15)<<3;
      *(uint4*)((pl?Bl:Bh)+r*136+c) = *(const uint4*)((pl?w2l_:w2h_) + (size_t)(cg*64+r)*F + c);
    }
    __syncthreads();
    f32x4 acc; acc[0]=0;acc[1]=0;acc[2]=0;acc[3]=0;
    #pragma unroll
    for (int k0=0;k0<F;k0+=32){
      bf16x8 a_h = *(const bf16x8*)&Hh[l15*136 + k0 + q8];
      bf16x8 a_l = *(const bf16x8*)&Hl[l15*136 + k0 + q8];
      bf16x8 b_h = *(const bf16x8*)&Bh[(w*16+l15)*136 + k0 + q8];
      bf16x8 b_l = *(const bf16x8*)&Bl[(w*16+l15)*136 + k0 + q8];
      acc = __builtin_amdgcn_mfma_f32_16x16x32_bf16(a_h, b_h, acc, 0,0,0);
      acc = __builtin_amdgcn_mfma_f32_16x16x32_bf16(a_h, b_l, acc, 0,0,0);
      acc = __builtin_amdgcn_mfma_f32_16x16x32_bf16(a_l, b_h, acc, 0,0,0);
    }
    int gc = cg*64 + w*16 + l15;
    float bb = b2[gc];
    #pragma unroll
    for (int r=0;r<4;r++){
      int grow = row0 + qrow + r;
      u16 v = f2bf(acc[r] + bb);
      size_t rowo = (size_t)grow*F;
      if (gc < F)        bufA16[(rowo + gc)*4 + 0]     = v;  // phi_vv
      else if (gc < 2*F) bufA16[(rowo + gc - F)*4 + 1] = v;  // phi_ss
      else               bufB16[(rowo + gc - 2*F)*2]   = v;  // phi_vs
    }
  }
}

// ------------------------------------------------- fused message aggregation
// 2 nodes/block (grid 4096); ALL 16 edges' gathers prefetched into registers.
__global__ __launch_bounds__(256) void k_agg(const uint4* __restrict__ ed_g,
                                             const uint2* __restrict__ bufA,
                                             const unsigned* __restrict__ bufB,
                                             const unsigned* __restrict__ rwp2,  // [11][3F]
                                             const u16* __restrict__ vi_h,
                                             const u16* __restrict__ vi_l,
                                             u16* __restrict__ vo_h,
                                             u16* __restrict__ vo_l,
                                             float* __restrict__ s,
                                             u16* __restrict__ s_h,
                                             u16* __restrict__ s_l){
  __shared__ uint4 ed4[128];        // 2 nodes x 16 edges x 64B
  int t = threadIdx.x;
  int half = t >> 7, f = t & 127;

  int nA = blockIdx.x * 2;
  if (t < 128) ed4[t] = ed_g[(size_t)nA*64 + t];
  __syncthreads();

  int n = nA + half;
  int base = half*64;

  // prefetch all 16 edges' payloads (48 VGPRs of loads in flight)
  uint2 pa[DEG]; unsigned pb[DEG];
  #pragma unroll
  for (int el=0;el<DEG;el++){
    int j = (int)(ed4[base+el*4+3].z & (N_NODES-1));
    pa[el] = bufA[(size_t)j*F + f];
    pb[el] = bufB[(size_t)j*F + f];
  }

  float ds=0.f, dv0=0.f, dv1=0.f, dv2=0.f;
  #pragma unroll
  for (int el=0;el<DEG;el++){
    uint4 q0 = ed4[base+el*4+0];
    uint4 q1 = ed4[base+el*4+1];
    uint4 q2 = ed4[base+el*4+2];
    uint4 q3 = ed4[base+el*4+3];
    unsigned rc[11] = {q0.x,q0.y,q0.z,q0.w, q1.x,q1.y,q1.z,q1.w, q2.x,q2.y,q2.z};
    float Wvv = 0.f, Wss = 0.f, Wvs = 0.f;
    #pragma unroll
    for (int r2=0;r2<11;r2++){
      Wvv = fdot2u(rc[r2], rwp2[r2*F3 + f],       Wvv);
      Wss = fdot2u(rc[r2], rwp2[r2*F3 + F + f],   Wss);
      Wvs = fdot2u(rc[r2], rwp2[r2*F3 + 2*F + f], Wvs);
    }
    float pvv = Wvv*lo_bf(pa[el].x), pss = Wss*hi_bf(pa[el].x), pvs = Wvs*lo_bf(pb[el]);
    ds += pss;
    dv0 += lo_bf(pa[el].y)*pvv + pvs*__uint_as_float(q2.w);
    dv1 += hi_bf(pa[el].y)*pvv + pvs*__uint_as_float(q3.x);
    dv2 += hi_bf(pb[el])  *pvv + pvs*__uint_as_float(q3.y);
  }
  size_t i = (size_t)n*F + f;
  const float inv = 1.f/DEG;
  float sv = s[i] + ds*inv;
  s[i] = sv;
  { u16 hb = f2bf(sv); s_h[i] = hb; s_l[i] = f2bf(sv - bf2f(hb)); }
  float o0 = bf2f(vi_h[i])              + bf2f(vi_l[i])              + dv0*inv;
  float o1 = bf2f(vi_h[NF+i])           + bf2f(vi_l[NF+i])           + dv1*inv;
  float o2 = bf2f(vi_h[2*(size_t)NF+i]) + bf2f(vi_l[2*(size_t)NF+i]) + dv2*inv;
  u16 h0=f2bf(o0), h1=f2bf(o1), h2=f2bf(o2);
  vo_h[i]=h0; vo_h[NF+i]=h1; vo_h[2*(size_t)NF+i]=h2;
  vo_l[i]=f2bf(o0-bf2f(h0)); vo_l[NF+i]=f2bf(o1-bf2f(h1)); vo_l[2*(size_t)NF+i]=f2bf(o2-bf2f(h2));
}

// ------------------------------------ fused Uv/Vv GEMM + dot/norm, 32x64 tile
__global__ __launch_bounds__(256) void k_uvdot(const u16* __restrict__ voh,
                                               const u16* __restrict__ vol,
                                               const u16* __restrict__ Bh_g,   // uvW [256][128]
                                               const u16* __restrict__ Bl_g,
                                               const float* __restrict__ s,
                                               u16* __restrict__ uvFb,         // [3][N][F] bf16
                                               float* __restrict__ dot,
                                               u16* __restrict__ ai_h,
                                               u16* __restrict__ ai_l){
  __shared__ u16 Ah[32*40], Al[32*40], BUh[64*40], BUl[64*40], BVh[64*40], BVl[64*40]; // 25.6KB
  int t = threadIdx.x;
  int row0 = blockIdx.y<<5, c0 = blockIdx.x<<6;
  int lane = t&63, w = t>>6;
  int qr = (w>>1)<<4, qc = (w&1)<<5;
  int l15 = lane&15, q8 = (lane>>4)<<3;
  int qrow = (lane>>4)<<2;
  int ap = t>>7, arem = t&127, ar = arem>>2, ac = (arem&3)<<3;
  f32x4 dA[2], nA2[2];
  dA[0][0]=0;dA[0][1]=0;dA[0][2]=0;dA[0][3]=0; dA[1]=dA[0];
  nA2[0]=dA[0]; nA2[1]=dA[0];

  for (int c=0;c<3;c++){
    f32x4 aU[2], aV[2];
    aU[0][0]=0;aU[0][1]=0;aU[0][2]=0;aU[0][3]=0; aU[1]=aU[0];
    aV[0]=aU[0]; aV[1]=aU[0];
    const u16* Asrc = (ap ? vol : voh) + (size_t)c*NF + (size_t)(row0+ar)*F + ac;
    u16* Adst = (ap ? Al : Ah) + ar*40 + ac;
    for (int k0=0;k0<F;k0+=32){
      *(uint4*)Adst = *(const uint4*)(Asrc + k0);
      #pragma unroll
      for (int q=0;q<4;q++){
        int idx = t + 256*q;
        int bp = idx>>8, rem = idx&255, br = rem>>2, bc = (rem&3)<<3;
        int grow = ((bp>>1) ? 128 : 0) + c0 + br;            // U rows then V rows
        const u16* Bsrc = ((bp&1) ? Bl_g : Bh_g) + (size_t)grow*F + k0 + bc;
        u16* Bdst;
        if (bp==0) Bdst = BUh; else if (bp==1) Bdst = BUl; else if (bp==2) Bdst = BVh; else Bdst = BVl;
        *(uint4*)(Bdst + br*40 + bc) = *(const uint4*)Bsrc;
      }
      __syncthreads();
      bf16x8 a_h = *(const bf16x8*)&Ah[(qr+l15)*40 + q8];
      bf16x8 a_l = *(const bf16x8*)&Al[(qr+l15)*40 + q8];
      #pragma unroll
      for (int nt=0;nt<2;nt++){
        int off = (qc+nt*16+l15)*40 + q8;
        bf16x8 bu_h = *(const bf16x8*)&BUh[off];
        bf16x8 bu_l = *(const bf16x8*)&BUl[off];
        bf16x8 bv_h = *(const bf16x8*)&BVh[off];
        bf16x8 bv_l = *(const bf16x8*)&BVl[off];
        aU[nt] = __builtin_amdgcn_mfma_f32_16x16x32_bf16(a_h, bu_h, aU[nt], 0,0,0);
        aU[nt] = __builtin_amdgcn_mfma_f32_16x16x32_bf16(a_h, bu_l, aU[nt], 0,0,0);
        aU[nt] = __builtin_amdgcn_mfma_f32_16x16x32_bf16(a_l, bu_h, aU[nt], 0,0,0);
        aV[nt] = __builtin_amdgcn_mfma_f32_16x16x32_bf16(a_h, bv_h, aV[nt], 0,0,0);
        aV[nt] = __builtin_amdgcn_mfma_f32_16x16x32_bf16(a_h, bv_l, aV[nt], 0,0,0);
        aV[nt] = __builtin_amdgcn_mfma_f32_16x16x32_bf16(a_l, bv_h, aV[nt], 0,0,0);
      }
      __syncthreads();
    }
    #pragma unroll
    for (int nt=0;nt<2;nt++){
      int gcol = c0 + qc + nt*16 + l15;
      #pragma unroll
      for (int r=0;r<4;r++){
        int grow = row0 + qr + qrow + r;
        float u = aU[nt][r], v = aV[nt][r];
        dA[nt][r] += u*v;
        nA2[nt][r] += v*v;
        uvFb[(size_t)c*NF + (size_t)grow*F + gcol] = f2bf(u);
      }
    }
  }
  #pragma unroll
  for (int nt=0;nt<2;nt++){
    int gcol = c0 + qc + nt*16 + l15;
    #pragma unroll
    for (int r=0;r<4;r++){
      int grow = row0 + qr + qrow + r;
      dot[(size_t)grow*F + gcol] = dA[nt][r];
      float vn = sqrtf(nA2[nt][r]);
      float sv = s[(size_t)grow*F + gcol];
      size_t b = (size_t)grow*256 + gcol;
      u16 h0 = f2bf(vn), h1 = f2bf(sv);
      ai_h[b] = h0;     ai_l[b] = f2bf(vn - bf2f(h0));
      ai_h[b+128] = h1; ai_l[b+128] = f2bf(sv - bf2f(h1));
    }
  }
}

// --------------- fused update MLP + apply: a = silu(ai@w1+b1)@w2+b2; apply epilogue
__global__ __launch_bounds__(256) void k_upd(const u16* __restrict__ ai_h,
                                             const u16* __restrict__ ai_l,
                                             const u16* __restrict__ w1h_,  // [128][256]
                                             const u16* __restrict__ w1l_,
                                             const u16* __restrict__ w2h_,  // [384][128]
                                             const u16* __restrict__ w2l_,
                                             const float* __restrict__ b1,
                                             const float* __restrict__ b2,
                                             const float* __restrict__ dot,
                                             const u16* __restrict__ uvFb,
                                             float* __restrict__ s,
                                             u16* __restrict__ s_h,
                                             u16* __restrict__ s_l,
                                             u16* __restrict__ v_h,
                                             u16* __restrict__ v_l,
                                             u16* __restrict__ bufA16,
                                             u16* __restrict__ bufB16,
                                             float* __restrict__ out){
  __shared__ u16 Ah[16*264], Al[16*264];     // ai, K=256 resident
  __shared__ u16 Hh[16*136], Hl[16*136];
  __shared__ u16 Bh[64*136], Bl[64*136];
  __shared__ __half aLDS[16*392];
  int t = threadIdx.x, lane = t&63, w = t>>6;
  int row0 = blockIdx.x<<4;
  int l15 = lane&15, q8 = (lane>>4)<<3, qrow = (lane>>4)<<2;

  #pragma unroll
  for (int q=0;q<4;q++){
    int id = t + 256*q; int pl = id>>9, rem = id&511, r = rem>>5, c = (rem&31)<<3;
    *(uint4*)((pl?Al:Ah)+r*264+c) = *(const uint4*)((pl?ai_l:ai_h) + (size_t)(row0+r)*256 + c);
  }

  for (int cg=0;cg<2;cg++){
    f32x4 acc; acc[0]=0;acc[1]=0;acc[2]=0;acc[3]=0;
    for (int kc=0;kc<4;kc++){
      __syncthreads();
      #pragma unroll
      for (int q=0;q<4;q++){
        int id = t + 256*q; int pl = id>>9, rem = id&511, r = rem>>3, c = (rem&7)<<3;
        *(uint4*)((pl?Bl:Bh)+r*136+c) =
            *(const uint4*)((pl?w1l_:w1h_) + (size_t)(cg*64+r)*256 + kc*64 + c);
      }
      __syncthreads();
      #pragma unroll
      for (int ks=0;ks<64;ks+=32){
        bf16x8 a_h = *(const bf16x8*)&Ah[l15*264 + kc*64 + ks + q8];
        bf16x8 a_l = *(const bf16x8*)&Al[l15*264 + kc*64 + ks + q8];
        bf16x8 b_h = *(const bf16x8*)&Bh[(w*16+l15)*136 + ks + q8];
        bf16x8 b_l = *(const bf16x8*)&Bl[(w*16+l15)*136 + ks + q8];
        acc = __builtin_amdgcn_mfma_f32_16x16x32_bf16(a_h, b_h, acc, 0,0,0);
        acc = __builtin_amdgcn_mfma_f32_16x16x32_bf16(a_h, b_l, acc, 0,0,0);
        acc = __builtin_amdgcn_mfma_f32_16x16x32_bf16(a_l, b_h, acc, 0,0,0);
      }
    }
    int col = cg*64 + w*16 + l15;
    float bb = b1[col];
    #pragma unroll
    for (int r=0;r<4;r++){
      float val = silu_f(acc[r] + bb);
      u16 hb = f2bf(val);
      Hh[(qrow+r)*136 + col] = hb;
      Hl[(qrow+r)*136 + col] = f2bf(val - bf2f(hb));
    }
  }

  for (int cg=0;cg<6;cg++){
    __syncthreads();
    #pragma unroll
    for (int q=0;q<8;q++){
      int id = t + 256*q; int pl = id>>10, rem = id&1023, r = rem>>4, c = (rem&15)<<3;
      *(uint4*)((pl?Bl:Bh)+r*136+c) = *(const uint4*)((pl?w2l_:w2h_) + (size_t)(cg*64+r)*F + c);
    }
    __syncthreads();
    f32x4 acc; acc[0]=0;acc[1]=0;acc[2]=0;acc[3]=0;
    #pragma unroll
    for (int k0=0;k0<F;k0+=32){
      bf16x8 a_h = *(const bf16x8*)&Hh[l15*136 + k0 + q8];
      bf16x8 a_l = *(const bf16x8*)&Hl[l15*136 + k0 + q8];
      bf16x8 b_h = *(const bf16x8*)&Bh[(w*16+l15)*136 + k0 + q8];
      bf16x8 b_l = *(const bf16x8*)&Bl[(w*16+l15)*136 + k0 + q8];
      acc = __builtin_amdgcn_mfma_f32_16x16x32_bf16(a_h, b_h, acc, 0,0,0);
      acc = __builtin_amdgcn_mfma_f32_16x16x32_bf16(a_h, b_l, acc, 0,0,0);
      acc = __builtin_amdgcn_mfma_f32_16x16x32_bf16(a_l, b_h, acc, 0,0,0);
    }
    int gc = cg*64 + w*16 + l15;
    float bb = b2[gc];
    #pragma unroll
    for (int r=0;r<4;r++)
      aLDS[(qrow+r)*392 + gc] = __float2half(acc[r] + bb);
  }
  __syncthreads();

  int f = t & 127, rh = (t>>7)*8;
  #pragma unroll
  for (int e=0;e<8;e++){
    int r = rh + e;
    int grow = row0 + r;
    size_t i = (size_t)grow*F + f;
    float avv = __half2float(aLDS[r*392 + f]);
    float asv = __half2float(aLDS[r*392 + F + f]);
    float ass = __half2float(aLDS[r*392 + 2*F + f]);
    float sv = s[i] + ass + asv*dot[i];
    s[i] = sv;
    u16 hb = f2bf(sv); s_h[i] = hb; s_l[i] = f2bf(sv - bf2f(hb));
    float nv0 = bf2f(v_h[i])              + bf2f(v_l[i])              + bf2f(uvFb[i])*avv;
    float nv1 = bf2f(v_h[NF+i])           + bf2f(v_l[NF+i])           + bf2f(uvFb[NF+i])*avv;
    float nv2 = bf2f(v_h[2*(size_t)NF+i]) + bf2f(v_l[2*(size_t)NF+i]) + bf2f(uvFb[2*(size_t)NF+i])*avv;
    u16 h0=f2bf(nv0), h1=f2bf(nv1), h2=f2bf(nv2);
    v_h[i]=h0; v_h[NF+i]=h1; v_h[2*(size_t)NF+i]=h2;
    v_l[i]=f2bf(nv0-bf2f(h0)); v_l[NF+i]=f2bf(nv1-bf2f(h1)); v_l[2*(size_t)NF+i]=f2bf(nv2-bf2f(h2));
    bufA16[(size_t)i*4+2] = h0; bufA16[(size_t)i*4+3] = h1;
    bufB16[(size_t)i*2+1] = h2;
    if (out){
      out[i] = sv;
      out[NF + (size_t)i*3 + 0] = nv0;
      out[NF + (size_t)i*3 + 1] = nv1;
      out[NF + (size_t)i*3 + 2] = nv2;
    }
  }
}

// ------------------------------------------------------------------ launch
extern "C" void kernel_launch(void* const* d_in, const int* in_sizes, int n_in,
                              void* d_out, int out_size, void* d_ws, size_t ws_size,
                              hipStream_t stream) {
  const int* atoms   = (const int*)d_in[0];
  const int* idxj    = (const int*)d_in[2];

  float* W = (float*)d_ws;
  size_t off = 64;
  int* flag = (int*)d_ws;
  #define ALLOCF(name, cnt) float* name = W+off; off += (((cnt)+63)&~(size_t)63)
  #define ALLOCU(name, cnt) u16* name = (u16*)(W+off); off += ((((cnt)+1)/2+63)&~(size_t)63)
  ALLOCF(c_mb1, NLAYER*F);
  ALLOCF(c_mb2, NLAYER*F3);
  ALLOCF(c_b1,  NLAYER*F);
  ALLOCF(c_b2,  NLAYER*F3);
  unsigned* c_rwp2 = (unsigned*)(W+off); off += ((NLAYER*11*F3+63)&~(size_t)63);
  uint4* edata = (uint4*)(W+off); off += (size_t)NEDGE*16;  // E x 64B = E*16 floats
  ALLOCU(w_mw1h, NLAYER*F*F);   ALLOCU(w_mw1l, NLAYER*F*F);
  ALLOCU(w_mw2h, NLAYER*F*F3);  ALLOCU(w_mw2l, NLAYER*F*F3);
  ALLOCU(w_uvh,  NLAYER*256*F); ALLOCU(w_uvl,  NLAYER*256*F);
  ALLOCU(w_w1h,  NLAYER*F*256); ALLOCU(w_w1l,  NLAYER*F*256);
  ALLOCU(w_w2h,  NLAYER*F*F3);  ALLOCU(w_w2l,  NLAYER*F*F3);
  uint2* bufA = (uint2*)(W+off); off += (size_t)2*NF;       // NF x 8B
  unsigned* bufB = (unsigned*)(W+off); off += (size_t)NF;   // NF x 4B
  ALLOCU(p0h, (size_t)3*NF); ALLOCU(p0l, (size_t)3*NF);
  ALLOCU(p1h, (size_t)3*NF); ALLOCU(p1l, (size_t)3*NF);
  ALLOCU(s_h,  NF); ALLOCU(s_l,  NF);
  ALLOCU(ai_h, (size_t)2*NF); ALLOCU(ai_l, (size_t)2*NF);
  ALLOCU(uvFb, (size_t)3*NF);
  ALLOCF(s,    NF);
  ALLOCF(dotb, NF);

  k_detect<<<1, 64, 0, stream>>>((const u16*)d_in[4], flag);
  k_prep<<<(PREP_TOTAL+255)/256, 256, 0, stream>>>(
      d_in[7], d_in[9], d_in[15], d_in[17],
      d_in[10], d_in[11],
      d_in[6], d_in[8], d_in[14], d_in[16],
      d_in[12], d_in[13],
      d_in[4], d_in[3], idxj,
      atoms, d_in[5],
      c_mb1, c_mb2, c_b1, c_b2, c_rwp2,
      w_mw1h, w_mw1l, w_mw2h, w_mw2l, w_w1h, w_w1l,
      w_w2h, w_w2l, w_uvh, w_uvl, edata,
      s, s_h, s_l, p0h, p0l, (u16*)bufA, (u16*)bufB, flag);

  for (int l=0; l<NLAYER; l++){
    u16* vih = (l & 1) ? p1h : p0h;
    u16* vil = (l & 1) ? p1l : p0l;
    u16* voh = (l & 1) ? p0h : p1h;
    u16* vol = (l & 1) ? p0l : p1l;
    // ---- message block ----
    k_msg<<<N_NODES/16, 256, 0, stream>>>(
        s_h, s_l,
        w_mw1h + (size_t)l*F*F,  w_mw1l + (size_t)l*F*F,
        w_mw2h + (size_t)l*F*F3, w_mw2l + (size_t)l*F*F3,
        c_mb1 + (size_t)l*F, c_mb2 + (size_t)l*F3,
        (u16*)bufA, (u16*)bufB);
    k_agg<<<N_NODES/2, 256, 0, stream>>>(
        edata, bufA, bufB, c_rwp2 + (size_t)l*11*F3,
        vih, vil, voh, vol, s, s_h, s_l);
    // ---- update block ----
    k_uvdot<<<dim3(2, N_NODES/32), 256, 0, stream>>>(
        voh, vol, w_uvh + (size_t)l*256*F, w_uvl + (size_t)l*256*F,
        s, uvFb, dotb, ai_h, ai_l);
    k_upd<<<N_NODES/16, 256, 0, stream>>>(
        ai_h, ai_l,
        w_w1h + (size_t)l*F*256, w_w1l + (size_t)l*F*256,
        w_w2h + (size_t)l*F*F3,  w_w2l + (size_t)l*F*F3,
        c_b1 + (size_t)l*F, c_b2 + (size_t)l*F3,
        dotb, uvFb, s, s_h, s_l, voh, vol,
        (u16*)bufA, (u16*)bufB,
        (l == NLAYER-1) ? (float*)d_out : nullptr);
  }
}

// Round 15
// 380.430 us; speedup vs baseline: 1.1239x; 1.1239x over previous
//
#include <hip/hip_runtime.h>
#include <hip/hip_fp16.h>

#define N_NODES 8192
#define DEG     16
#define NEDGE   (N_NODES*DEG)
#define F       128
#define F3      384
#define RBF     20
#define NLAYER  3
#define NF      (N_NODES*F)
#define PI_F    3.14159265358979f

typedef unsigned short u16;
typedef __bf16 bf16x8 __attribute__((ext_vector_type(8)));
typedef float  f32x4  __attribute__((ext_vector_type(4)));
typedef _Float16 f16x2 __attribute__((ext_vector_type(2)));

__device__ __forceinline__ float bf2f(u16 u){ return __uint_as_float(((unsigned)u)<<16); }
__device__ __forceinline__ u16 f2bf(float f){
  unsigned x = __float_as_uint(f);
  unsigned r = (x + 0x7FFFu + ((x>>16)&1u)) >> 16;   // RNE
  return (u16)r;
}
__device__ __forceinline__ float lo_bf(unsigned u){ return __uint_as_float(u<<16); }
__device__ __forceinline__ float hi_bf(unsigned u){ return __uint_as_float(u & 0xFFFF0000u); }
__device__ __forceinline__ float silu_f(float x){ return x / (1.f + __expf(-x)); }
__device__ __forceinline__ float ldsrc(const void* src, int i, int bf){
  return bf ? bf2f(((const u16*)src)[i]) : ((const float*)src)[i];
}
__device__ __forceinline__ unsigned packh2(float a, float b){
  return (unsigned)__half_as_ushort(__float2half(a)) |
         ((unsigned)__half_as_ushort(__float2half(b)) << 16);
}
// v_dot2_f32_f16: c += a.x*b.x + a.y*b.y  (fp32 accumulate, 1 VALU op)
__device__ __forceinline__ float fdot2u(unsigned a, unsigned b, float c){
  return __builtin_amdgcn_fdot2(__builtin_bit_cast(f16x2, a),
                                __builtin_bit_cast(f16x2, b), c, false);
}

// ------------------------------------------------------------ dtype detect
__global__ void k_detect(const u16* __restrict__ rd, int* __restrict__ flag){
  if (threadIdx.x == 0 && blockIdx.x == 0){
    int ok = 1;
    for (int i = 0; i < 128; i++){
      float v = bf2f(rd[2*i]);
      if (!(v > 0.01f && v < 4.0f)) { ok = 0; break; }
    }
    *flag = ok;   // 1 = inputs bf16, 0 = fp32
  }
}

// ------------------------------------------- split helper: [L][K][N] -> [L][N][K] hi/lo
__device__ __forceinline__ void splitw(const void* src, u16* bh, u16* bl,
                                       int i, int K, int Ncol, int bf){
  int kn = K*Ncol; int l = i/kn; int r = i - l*kn; int k = r/Ncol; int n = r - k*Ncol;
  float w = ldsrc(src, i, bf);
  u16 h = f2bf(w);
  size_t o = (size_t)l*kn + (size_t)n*K + k;
  bh[o] = h; bl[o] = f2bf(w - bf2f(h));
}

// -------------------------------------- fused preamble (weights + edges + node init)
__global__ __launch_bounds__(256) void k_prep(
    const void* mb1, const void* mb2, const void* b1, const void* b2,
    const void* rw,  const void* rb,
    const void* mw1, const void* mw2, const void* w1, const void* w2,
    const void* Uw,  const void* Vw,
    const void* dist, const void* dirv, const int* __restrict__ idxj,
    const int* __restrict__ atoms, const void* __restrict__ emb,
    float* c_mb1, float* c_mb2, float* c_b1, float* c_b2,
    unsigned* rwp2,                 // [L][11][3F]
    u16* mw1h, u16* mw1l, u16* mw2h, u16* mw2l, u16* w1h, u16* w1l,
    u16* w2h, u16* w2l, u16* uvh, u16* uvl,
    uint4* edata,                   // [E][4]
    float* s, u16* s_h, u16* s_l,
    u16* p0h, u16* p0l, u16* bufA16, u16* bufB16,
    const int* __restrict__ flag){
  int i = blockIdx.x*256 + threadIdx.x;
  int bf = *flag;
  const int S0=NLAYER*F, S1=NLAYER*F3, S2=NLAYER*F, S3=NLAYER*F3;
  const int S4=NLAYER*11*F3;
  const int S5=NLAYER*F*F, S6=NLAYER*F*F3, S7=NLAYER*2*F*F, S8=NLAYER*F*F3, S9=NLAYER*256*F;
  if (i < S0){ c_mb1[i]=ldsrc(mb1,i,bf); return; } i-=S0;
  if (i < S1){ c_mb2[i]=ldsrc(mb2,i,bf); return; } i-=S1;
  if (i < S2){ c_b1[i] =ldsrc(b1, i,bf); return; } i-=S2;
  if (i < S3){ c_b2[i] =ldsrc(b2, i,bf); return; } i-=S3;
  if (i < S4){
    int l = i/(11*F3); int r = i - l*(11*F3); int r2 = r/F3; int col = r - r2*F3;
    float w0, w1v;
    if (r2 < 10){
      w0  = ldsrc(rw, (l*RBF + 2*r2  )*F3 + col, bf);
      w1v = ldsrc(rw, (l*RBF + 2*r2+1)*F3 + col, bf);
    } else {
      w0  = ldsrc(rb, l*F3 + col, bf);
      w1v = 0.f;
    }
    rwp2[i] = packh2(w0, w1v);
    return;
  } i-=S4;
  if (i < S5){ splitw(mw1, mw1h, mw1l, i, F,   F,  bf); return; } i-=S5;
  if (i < S6){ splitw(mw2, mw2h, mw2l, i, F,   F3, bf); return; } i-=S6;
  if (i < S7){ splitw(w1,  w1h,  w1l,  i, 2*F, F,  bf); return; } i-=S7;
  if (i < S8){ splitw(w2,  w2h,  w2l,  i, F,   F3, bf); return; } i-=S8;
  if (i < S9){
    int l=i/(256*F); int r=i-l*(256*F); int n=r>>7; int k=r&127;
    int si=(l*F+k)*F+(n&127);
    float w = ldsrc((n<128)?Uw:Vw, si, bf);
    u16 h=f2bf(w); uvh[i]=h; uvl[i]=f2bf(w-bf2f(h));
    return;
  } i-=S9;
  if (i < NEDGE){
    int e = i;
    float d = ldsrc(dist, e, bf);
    float th = PI_F*d*(1.f/3.f);
    float c  = __cosf(th);
    float s1 = __sinf(th);
    float cut = 0.5f*(c + 1.0f);
    float ic = cut/d;
    // Chebyshev recurrence: sin((k+1)th) = 2c*sin(k th) - sin((k-1) th)
    float sk[RBF+1];
    sk[0] = s1; float sm1 = 0.f, s0 = s1;
    #pragma unroll
    for (int k=1;k<=RBF;k++){ float sn = 2.f*c*s0 - sm1; sk[k-1] = s0; sm1 = s0; s0 = sn; }
    unsigned o[16];
    #pragma unroll
    for (int r2=0;r2<10;r2++)
      o[r2] = packh2(sk[2*r2]*ic, sk[2*r2+1]*ic);
    o[10] = packh2(cut, 0.f);
    o[11] = __float_as_uint(ldsrc(dirv, e*3+0, bf));
    o[12] = __float_as_uint(ldsrc(dirv, e*3+1, bf));
    o[13] = __float_as_uint(ldsrc(dirv, e*3+2, bf));
    o[14] = (unsigned)idxj[e];
    o[15] = 0;
    uint4* dst = edata + (size_t)e*4;
    dst[0] = make_uint4(o[0],o[1],o[2],o[3]);
    dst[1] = make_uint4(o[4],o[5],o[6],o[7]);
    dst[2] = make_uint4(o[8],o[9],o[10],o[11]);
    dst[3] = make_uint4(o[12],o[13],o[14],o[15]);
    return;
  } i-=NEDGE;
  if (i < NF){                      // node init
    int n = i >> 7, f = i & 127;
    float sv = ldsrc(emb, atoms[n]*F + f, bf);
    s[i] = sv;
    u16 hb = f2bf(sv); s_h[i] = hb; s_l[i] = f2bf(sv - bf2f(hb));
    p0h[i]=0; p0h[NF+i]=0; p0h[2*(size_t)NF+i]=0;
    p0l[i]=0; p0l[NF+i]=0; p0l[2*(size_t)NF+i]=0;
    bufA16[(size_t)i*4+2]=0; bufA16[(size_t)i*4+3]=0;
    bufB16[(size_t)i*2+1]=0;
  }
}
#define PREP_TOTAL (NLAYER*(F+F3+F+F3+11*F3+F*F+F*F3+2*F*F+F*F3+256*F) + NEDGE + NF)

// --------------------------------- fused message MLP: phi = silu(s@mw1+b1)@mw2+b2
__global__ __launch_bounds__(256) void k_msg(const u16* __restrict__ s_h,
                                             const u16* __restrict__ s_l,
                                             const u16* __restrict__ w1h_,  // [128][128]
                                             const u16* __restrict__ w1l_,
                                             const u16* __restrict__ w2h_,  // [384][128]
                                             const u16* __restrict__ w2l_,
                                             const float* __restrict__ b1,
                                             const float* __restrict__ b2,
                                             u16* __restrict__ bufA16,
                                             u16* __restrict__ bufB16){
  __shared__ u16 Ah[16*136], Al[16*136];
  __shared__ u16 Hh[16*136], Hl[16*136];
  __shared__ u16 Bh[64*136], Bl[64*136];
  int t = threadIdx.x, lane = t&63, w = t>>6;
  int row0 = blockIdx.x<<4;
  int l15 = lane&15, q8 = (lane>>4)<<3, qrow = (lane>>4)<<2;

  #pragma unroll
  for (int q=0;q<2;q++){
    int id = t + 256*q; int pl = id>>8, rem = id&255, r = rem>>4, c = (rem&15)<<3;
    *(uint4*)((pl?Al:Ah)+r*136+c) = *(const uint4*)((pl?s_l:s_h) + (size_t)(row0+r)*F + c);
  }

  for (int cg=0;cg<2;cg++){
    __syncthreads();
    #pragma unroll
    for (int q=0;q<8;q++){
      int id = t + 256*q; int pl = id>>10, rem = id&1023, r = rem>>4, c = (rem&15)<<3;
      *(uint4*)((pl?Bl:Bh)+r*136+c) = *(const uint4*)((pl?w1l_:w1h_) + (size_t)(cg*64+r)*F + c);
    }
    __syncthreads();
    f32x4 acc; acc[0]=0;acc[1]=0;acc[2]=0;acc[3]=0;
    #pragma unroll
    for (int k0=0;k0<F;k0+=32){
      bf16x8 a_h = *(const bf16x8*)&Ah[l15*136 + k0 + q8];
      bf16x8 a_l = *(const bf16x8*)&Al[l15*136 + k0 + q8];
      bf16x8 b_h = *(const bf16x8*)&Bh[(w*16+l15)*136 + k0 + q8];
      bf16x8 b_l = *(const bf16x8*)&Bl[(w*16+l15)*136 + k0 + q8];
      acc = __builtin_amdgcn_mfma_f32_16x16x32_bf16(a_h, b_h, acc, 0,0,0);
      acc = __builtin_amdgcn_mfma_f32_16x16x32_bf16(a_h, b_l, acc, 0,0,0);
      acc = __builtin_amdgcn_mfma_f32_16x16x32_bf16(a_l, b_h, acc, 0,0,0);
    }
    int col = cg*64 + w*16 + l15;
    float bb = b1[col];
    #pragma unroll
    for (int r=0;r<4;r++){
      float val = silu_f(acc[r] + bb);
      u16 hb = f2bf(val);
      Hh[(qrow+r)*136 + col] = hb;
      Hl[(qrow+r)*136 + col] = f2bf(val - bf2f(hb));
    }
  }

  for (int cg=0;cg<6;cg++){
    __syncthreads();
    #pragma unroll
    for (int q=0;q<8;q++){
      int id = t + 256*q; int pl = id>>10, rem = id&1023, r = rem>>4, c = (rem&15)<<3;
      *(uint4*)((pl?Bl:Bh)+r*136+c) = *(const uint4*)((pl?w2l_:w2h_) + (size_t)(cg*64+r)*F + c);
    }
    __syncthreads();
    f32x4 acc; acc[0]=0;acc[1]=0;acc[2]=0;acc[3]=0;
    #pragma unroll
    for (int k0=0;k0<F;k0+=32){
      bf16x8 a_h = *(const bf16x8*)&Hh[l15*136 + k0 + q8];
      bf16x8 a_l = *(const bf16x8*)&Hl[l15*136 + k0 + q8];
      bf16x8 b_h = *(const bf16x8*)&Bh[(w*16+l15)*136 + k0 + q8];
      bf16x8 b_l = *(const bf16x8*)&Bl[(w*16+l15)*136 + k0 + q8];
      acc = __builtin_amdgcn_mfma_f32_16x16x32_bf16(a_h, b_h, acc, 0,0,0);
      acc = __builtin_amdgcn_mfma_f32_16x16x32_bf16(a_h, b_l, acc, 0,0,0);
      acc = __builtin_amdgcn_mfma_f32_16x16x32_bf16(a_l, b_h, acc, 0,0,0);
    }
    int gc = cg*64 + w*16 + l15;
    float bb = b2[gc];
    #pragma unroll
    for (int r=0;r<4;r++){
      int grow = row0 + qrow + r;
      u16 v = f2bf(acc[r] + bb);
      size_t rowo = (size_t)grow*F;
      if (gc < F)        bufA16[(rowo + gc)*4 + 0]     = v;  // phi_vv
      else if (gc < 2*F) bufA16[(rowo + gc - F)*4 + 1] = v;  // phi_ss
      else               bufB16[(rowo + gc - 2*F)*2]   = v;  // phi_vs
    }
  }
}

// ------------------------------------------------- fused message aggregation
// 2 nodes/block (grid 4096); 2 gathers/edge, 1-deep prefetch; fdot2 W-recon.
// (round-13 proven form: VGPR~40, occupancy ~58%)
__global__ __launch_bounds__(256) void k_agg(const uint4* __restrict__ ed_g,
                                             const uint2* __restrict__ bufA,
                                             const unsigned* __restrict__ bufB,
                                             const unsigned* __restrict__ rwp2,  // [11][3F]
                                             const u16* __restrict__ vi_h,
                                             const u16* __restrict__ vi_l,
                                             u16* __restrict__ vo_h,
                                             u16* __restrict__ vo_l,
                                             float* __restrict__ s,
                                             u16* __restrict__ s_h,
                                             u16* __restrict__ s_l){
  __shared__ uint4 ed4[128];        // 2 nodes x 16 edges x 64B
  int t = threadIdx.x;
  int half = t >> 7, f = t & 127;

  unsigned rw2[3][11];
  #pragma unroll
  for (int r2=0;r2<11;r2++){
    rw2[0][r2] = rwp2[r2*F3 + f];
    rw2[1][r2] = rwp2[r2*F3 + F + f];
    rw2[2][r2] = rwp2[r2*F3 + 2*F + f];
  }

  int nA = blockIdx.x * 2;
  if (t < 128) ed4[t] = ed_g[(size_t)nA*64 + t];
  __syncthreads();

  int n = nA + half;
  int base = half*64;
  float ds=0.f, dv0=0.f, dv1=0.f, dv2=0.f;

  int j0 = (int)(ed4[base+3].z & (N_NODES-1));
  uint2    pa = bufA[(size_t)j0*F + f];
  unsigned pb = bufB[(size_t)j0*F + f];
  for (int el=0;el<DEG;el++){
    uint2 cpa = pa; unsigned cpb = pb;
    if (el+1 < DEG){
      int j1 = (int)(ed4[base+(el+1)*4+3].z & (N_NODES-1));
      pa = bufA[(size_t)j1*F + f];
      pb = bufB[(size_t)j1*F + f];
    }
    uint4 q0 = ed4[base+el*4+0];
    uint4 q1 = ed4[base+el*4+1];
    uint4 q2 = ed4[base+el*4+2];
    uint4 q3 = ed4[base+el*4+3];
    unsigned rc[11] = {q0.x,q0.y,q0.z,q0.w, q1.x,q1.y,q1.z,q1.w, q2.x,q2.y,q2.z};
    float Wvv = 0.f, Wss = 0.f, Wvs = 0.f;
    #pragma unroll
    for (int r2=0;r2<11;r2++){
      Wvv = fdot2u(rc[r2], rw2[0][r2], Wvv);
      Wss = fdot2u(rc[r2], rw2[1][r2], Wss);
      Wvs = fdot2u(rc[r2], rw2[2][r2], Wvs);
    }
    float pvv = Wvv*lo_bf(cpa.x), pss = Wss*hi_bf(cpa.x), pvs = Wvs*lo_bf(cpb);
    ds += pss;
    dv0 += lo_bf(cpa.y)*pvv + pvs*__uint_as_float(q2.w);
    dv1 += hi_bf(cpa.y)*pvv + pvs*__uint_as_float(q3.x);
    dv2 += hi_bf(cpb)  *pvv + pvs*__uint_as_float(q3.y);
  }
  size_t i = (size_t)n*F + f;
  const float inv = 1.f/DEG;
  float sv = s[i] + ds*inv;
  s[i] = sv;
  { u16 hb = f2bf(sv); s_h[i] = hb; s_l[i] = f2bf(sv - bf2f(hb)); }
  float o0 = bf2f(vi_h[i])              + bf2f(vi_l[i])              + dv0*inv;
  float o1 = bf2f(vi_h[NF+i])           + bf2f(vi_l[NF+i])           + dv1*inv;
  float o2 = bf2f(vi_h[2*(size_t)NF+i]) + bf2f(vi_l[2*(size_t)NF+i]) + dv2*inv;
  u16 h0=f2bf(o0), h1=f2bf(o1), h2=f2bf(o2);
  vo_h[i]=h0; vo_h[NF+i]=h1; vo_h[2*(size_t)NF+i]=h2;
  vo_l[i]=f2bf(o0-bf2f(h0)); vo_l[NF+i]=f2bf(o1-bf2f(h1)); vo_l[2*(size_t)NF+i]=f2bf(o2-bf2f(h2));
}

// ------------------------------------ fused Uv/Vv GEMM + dot/norm, 32x64 tile
__global__ __launch_bounds__(256) void k_uvdot(const u16* __restrict__ voh,
                                               const u16* __restrict__ vol,
                                               const u16* __restrict__ Bh_g,   // uvW [256][128]
                                               const u16* __restrict__ Bl_g,
                                               const float* __restrict__ s,
                                               u16* __restrict__ uvFb,         // [3][N][F] bf16
                                               float* __restrict__ dot,
                                               u16* __restrict__ ai_h,
                                               u16* __restrict__ ai_l){
  __shared__ u16 Ah[32*40], Al[32*40], BUh[64*40], BUl[64*40], BVh[64*40], BVl[64*40]; // 25.6KB
  int t = threadIdx.x;
  int row0 = blockIdx.y<<5, c0 = blockIdx.x<<6;
  int lane = t&63, w = t>>6;
  int qr = (w>>1)<<4, qc = (w&1)<<5;
  int l15 = lane&15, q8 = (lane>>4)<<3;
  int qrow = (lane>>4)<<2;
  int ap = t>>7, arem = t&127, ar = arem>>2, ac = (arem&3)<<3;
  f32x4 dA[2], nA2[2];
  dA[0][0]=0;dA[0][1]=0;dA[0][2]=0;dA[0][3]=0; dA[1]=dA[0];
  nA2[0]=dA[0]; nA2[1]=dA[0];

  for (int c=0;c<3;c++){
    f32x4 aU[2], aV[2];
    aU[0][0]=0;aU[0][1]=0;aU[0][2]=0;aU[0][3]=0; aU[1]=aU[0];
    aV[0]=aU[0]; aV[1]=aU[0];
    const u16* Asrc = (ap ? vol : voh) + (size_t)c*NF + (size_t)(row0+ar)*F + ac;
    u16* Adst = (ap ? Al : Ah) + ar*40 + ac;
    for (int k0=0;k0<F;k0+=32){
      *(uint4*)Adst = *(const uint4*)(Asrc + k0);
      #pragma unroll
      for (int q=0;q<4;q++){
        int idx = t + 256*q;
        int bp = idx>>8, rem = idx&255, br = rem>>2, bc = (rem&3)<<3;
        int grow = ((bp>>1) ? 128 : 0) + c0 + br;            // U rows then V rows
        const u16* Bsrc = ((bp&1) ? Bl_g : Bh_g) + (size_t)grow*F + k0 + bc;
        u16* Bdst;
        if (bp==0) Bdst = BUh; else if (bp==1) Bdst = BUl; else if (bp==2) Bdst = BVh; else Bdst = BVl;
        *(uint4*)(Bdst + br*40 + bc) = *(const uint4*)Bsrc;
      }
      __syncthreads();
      bf16x8 a_h = *(const bf16x8*)&Ah[(qr+l15)*40 + q8];
      bf16x8 a_l = *(const bf16x8*)&Al[(qr+l15)*40 + q8];
      #pragma unroll
      for (int nt=0;nt<2;nt++){
        int off = (qc+nt*16+l15)*40 + q8;
        bf16x8 bu_h = *(const bf16x8*)&BUh[off];
        bf16x8 bu_l = *(const bf16x8*)&BUl[off];
        bf16x8 bv_h = *(const bf16x8*)&BVh[off];
        bf16x8 bv_l = *(const bf16x8*)&BVl[off];
        aU[nt] = __builtin_amdgcn_mfma_f32_16x16x32_bf16(a_h, bu_h, aU[nt], 0,0,0);
        aU[nt] = __builtin_amdgcn_mfma_f32_16x16x32_bf16(a_h, bu_l, aU[nt], 0,0,0);
        aU[nt] = __builtin_amdgcn_mfma_f32_16x16x32_bf16(a_l, bu_h, aU[nt], 0,0,0);
        aV[nt] = __builtin_amdgcn_mfma_f32_16x16x32_bf16(a_h, bv_h, aV[nt], 0,0,0);
        aV[nt] = __builtin_amdgcn_mfma_f32_16x16x32_bf16(a_h, bv_l, aV[nt], 0,0,0);
        aV[nt] = __builtin_amdgcn_mfma_f32_16x16x32_bf16(a_l, bv_h, aV[nt], 0,0,0);
      }
      __syncthreads();
    }
    #pragma unroll
    for (int nt=0;nt<2;nt++){
      int gcol = c0 + qc + nt*16 + l15;
      #pragma unroll
      for (int r=0;r<4;r++){
        int grow = row0 + qr + qrow + r;
        float u = aU[nt][r], v = aV[nt][r];
        dA[nt][r] += u*v;
        nA2[nt][r] += v*v;
        uvFb[(size_t)c*NF + (size_t)grow*F + gcol] = f2bf(u);
      }
    }
  }
  #pragma unroll
  for (int nt=0;nt<2;nt++){
    int gcol = c0 + qc + nt*16 + l15;
    #pragma unroll
    for (int r=0;r<4;r++){
      int grow = row0 + qr + qrow + r;
      dot[(size_t)grow*F + gcol] = dA[nt][r];
      float vn = sqrtf(nA2[nt][r]);
      float sv = s[(size_t)grow*F + gcol];
      size_t b = (size_t)grow*256 + gcol;
      u16 h0 = f2bf(vn), h1 = f2bf(sv);
      ai_h[b] = h0;     ai_l[b] = f2bf(vn - bf2f(h0));
      ai_h[b+128] = h1; ai_l[b+128] = f2bf(sv - bf2f(h1));
    }
  }
}

// --------------- fused update MLP + apply: a = silu(ai@w1+b1)@w2+b2; apply epilogue
__global__ __launch_bounds__(256) void k_upd(const u16* __restrict__ ai_h,
                                             const u16* __restrict__ ai_l,
                                             const u16* __restrict__ w1h_,  // [128][256]
                                             const u16* __restrict__ w1l_,
                                             const u16* __restrict__ w2h_,  // [384][128]
                                             const u16* __restrict__ w2l_,
                                             const float* __restrict__ b1,
                                             const float* __restrict__ b2,
                                             const float* __restrict__ dot,
                                             const u16* __restrict__ uvFb,
                                             float* __restrict__ s,
                                             u16* __restrict__ s_h,
                                             u16* __restrict__ s_l,
                                             u16* __restrict__ v_h,
                                             u16* __restrict__ v_l,
                                             u16* __restrict__ bufA16,
                                             u16* __restrict__ bufB16,
                                             float* __restrict__ out){
  __shared__ u16 Ah[16*264], Al[16*264];     // ai, K=256 resident
  __shared__ u16 Hh[16*136], Hl[16*136];
  __shared__ u16 Bh[64*136], Bl[64*136];
  __shared__ __half aLDS[16*392];
  int t = threadIdx.x, lane = t&63, w = t>>6;
  int row0 = blockIdx.x<<4;
  int l15 = lane&15, q8 = (lane>>4)<<3, qrow = (lane>>4)<<2;

  #pragma unroll
  for (int q=0;q<4;q++){
    int id = t + 256*q; int pl = id>>9, rem = id&511, r = rem>>5, c = (rem&31)<<3;
    *(uint4*)((pl?Al:Ah)+r*264+c) = *(const uint4*)((pl?ai_l:ai_h) + (size_t)(row0+r)*256 + c);
  }

  for (int cg=0;cg<2;cg++){
    f32x4 acc; acc[0]=0;acc[1]=0;acc[2]=0;acc[3]=0;
    for (int kc=0;kc<4;kc++){
      __syncthreads();
      #pragma unroll
      for (int q=0;q<4;q++){
        int id = t + 256*q; int pl = id>>9, rem = id&511, r = rem>>3, c = (rem&7)<<3;
        *(uint4*)((pl?Bl:Bh)+r*136+c) =
            *(const uint4*)((pl?w1l_:w1h_) + (size_t)(cg*64+r)*256 + kc*64 + c);
      }
      __syncthreads();
      #pragma unroll
      for (int ks=0;ks<64;ks+=32){
        bf16x8 a_h = *(const bf16x8*)&Ah[l15*264 + kc*64 + ks + q8];
        bf16x8 a_l = *(const bf16x8*)&Al[l15*264 + kc*64 + ks + q8];
        bf16x8 b_h = *(const bf16x8*)&Bh[(w*16+l15)*136 + ks + q8];
        bf16x8 b_l = *(const bf16x8*)&Bl[(w*16+l15)*136 + ks + q8];
        acc = __builtin_amdgcn_mfma_f32_16x16x32_bf16(a_h, b_h, acc, 0,0,0);
        acc = __builtin_amdgcn_mfma_f32_16x16x32_bf16(a_h, b_l, acc, 0,0,0);
        acc = __builtin_amdgcn_mfma_f32_16x16x32_bf16(a_l, b_h, acc, 0,0,0);
      }
    }
    int col = cg*64 + w*16 + l15;
    float bb = b1[col];
    #pragma unroll
    for (int r=0;r<4;r++){
      float val = silu_f(acc[r] + bb);
      u16 hb = f2bf(val);
      Hh[(qrow+r)*136 + col] = hb;
      Hl[(qrow+r)*136 + col] = f2bf(val - bf2f(hb));
    }
  }

  for (int cg=0;cg<6;cg++){
    __syncthreads();
    #pragma unroll
    for (int q=0;q<8;q++){
      int id = t + 256*q; int pl = id>>10, rem = id&1023, r = rem>>4, c = (rem&15)<<3;
      *(uint4*)((pl?Bl:Bh)+r*136+c) = *(const uint4*)((pl?w2l_:w2h_) + (size_t)(cg*64+r)*F + c);
    }
    __syncthreads();
    f32x4 acc; acc[0]=0;acc[1]=0;acc[2]=0;acc[3]=0;
    #pragma unroll
    for (int k0=0;k0<F;k0+=32){
      bf16x8 a_h = *(const bf16x8*)&Hh[l15*136 + k0 + q8];
      bf16x8 a_l = *(const bf16x8*)&Hl[l15*136 + k0 + q8];
      bf16x8 b_h = *(const bf16x8*)&Bh[(w*16+l15)*136 + k0 + q8];
      bf16x8 b_l = *(const bf16x8*)&Bl[(w*16+l15)*136 + k0 + q8];
      acc = __builtin_amdgcn_mfma_f32_16x16x32_bf16(a_h, b_h, acc, 0,0,0);
      acc = __builtin_amdgcn_mfma_f32_16x16x32_bf16(a_h, b_l, acc, 0,0,0);
      acc = __builtin_amdgcn_mfma_f32_16x16x32_bf16(a_l, b_h, acc, 0,0,0);
    }
    int gc = cg*64 + w*16 + l15;
    float bb = b2[gc];
    #pragma unroll
    for (int r=0;r<4;r++)
      aLDS[(qrow+r)*392 + gc] = __float2half(acc[r] + bb);
  }
  __syncthreads();

  int f = t & 127, rh = (t>>7)*8;
  #pragma unroll
  for (int e=0;e<8;e++){
    int r = rh + e;
    int grow = row0 + r;
    size_t i = (size_t)grow*F + f;
    float avv = __half2float(aLDS[r*392 + f]);
    float asv = __half2float(aLDS[r*392 + F + f]);
    float ass = __half2float(aLDS[r*392 + 2*F + f]);
    float sv = s[i] + ass + asv*dot[i];
    s[i] = sv;
    u16 hb = f2bf(sv); s_h[i] = hb; s_l[i] = f2bf(sv - bf2f(hb));
    float nv0 = bf2f(v_h[i])              + bf2f(v_l[i])              + bf2f(uvFb[i])*avv;
    float nv1 = bf2f(v_h[NF+i])           + bf2f(v_l[NF+i])           + bf2f(uvFb[NF+i])*avv;
    float nv2 = bf2f(v_h[2*(size_t)NF+i]) + bf2f(v_l[2*(size_t)NF+i]) + bf2f(uvFb[2*(size_t)NF+i])*avv;
    u16 h0=f2bf(nv0), h1=f2bf(nv1), h2=f2bf(nv2);
    v_h[i]=h0; v_h[NF+i]=h1; v_h[2*(size_t)NF+i]=h2;
    v_l[i]=f2bf(nv0-bf2f(h0)); v_l[NF+i]=f2bf(nv1-bf2f(h1)); v_l[2*(size_t)NF+i]=f2bf(nv2-bf2f(h2));
    bufA16[(size_t)i*4+2] = h0; bufA16[(size_t)i*4+3] = h1;
    bufB16[(size_t)i*2+1] = h2;
    if (out){
      out[i] = sv;
      out[NF + (size_t)i*3 + 0] = nv0;
      out[NF + (size_t)i*3 + 1] = nv1;
      out[NF + (size_t)i*3 + 2] = nv2;
    }
  }
}

// ------------------------------------------------------------------ launch
extern "C" void kernel_launch(void* const* d_in, const int* in_sizes, int n_in,
                              void* d_out, int out_size, void* d_ws, size_t ws_size,
                              hipStream_t stream) {
  const int* atoms   = (const int*)d_in[0];
  const int* idxj    = (const int*)d_in[2];

  float* W = (float*)d_ws;
  size_t off = 64;
  int* flag = (int*)d_ws;
  #define ALLOCF(name, cnt) float* name = W+off; off += (((cnt)+63)&~(size_t)63)
  #define ALLOCU(name, cnt) u16* name = (u16*)(W+off); off += ((((cnt)+1)/2+63)&~(size_t)63)
  ALLOCF(c_mb1, NLAYER*F);
  ALLOCF(c_mb2, NLAYER*F3);
  ALLOCF(c_b1,  NLAYER*F);
  ALLOCF(c_b2,  NLAYER*F3);
  unsigned* c_rwp2 = (unsigned*)(W+off); off += ((NLAYER*11*F3+63)&~(size_t)63);
  uint4* edata = (uint4*)(W+off); off += (size_t)NEDGE*16;  // E x 64B = E*16 floats
  ALLOCU(w_mw1h, NLAYER*F*F);   ALLOCU(w_mw1l, NLAYER*F*F);
  ALLOCU(w_mw2h, NLAYER*F*F3);  ALLOCU(w_mw2l, NLAYER*F*F3);
  ALLOCU(w_uvh,  NLAYER*256*F); ALLOCU(w_uvl,  NLAYER*256*F);
  ALLOCU(w_w1h,  NLAYER*F*256); ALLOCU(w_w1l,  NLAYER*F*256);
  ALLOCU(w_w2h,  NLAYER*F*F3);  ALLOCU(w_w2l,  NLAYER*F*F3);
  uint2* bufA = (uint2*)(W+off); off += (size_t)2*NF;       // NF x 8B
  unsigned* bufB = (unsigned*)(W+off); off += (size_t)NF;   // NF x 4B
  ALLOCU(p0h, (size_t)3*NF); ALLOCU(p0l, (size_t)3*NF);
  ALLOCU(p1h, (size_t)3*NF); ALLOCU(p1l, (size_t)3*NF);
  ALLOCU(s_h,  NF); ALLOCU(s_l,  NF);
  ALLOCU(ai_h, (size_t)2*NF); ALLOCU(ai_l, (size_t)2*NF);
  ALLOCU(uvFb, (size_t)3*NF);
  ALLOCF(s,    NF);
  ALLOCF(dotb, NF);

  k_detect<<<1, 64, 0, stream>>>((const u16*)d_in[4], flag);
  k_prep<<<(PREP_TOTAL+255)/256, 256, 0, stream>>>(
      d_in[7], d_in[9], d_in[15], d_in[17],
      d_in[10], d_in[11],
      d_in[6], d_in[8], d_in[14], d_in[16],
      d_in[12], d_in[13],
      d_in[4], d_in[3], idxj,
      atoms, d_in[5],
      c_mb1, c_mb2, c_b1, c_b2, c_rwp2,
      w_mw1h, w_mw1l, w_mw2h, w_mw2l, w_w1h, w_w1l,
      w_w2h, w_w2l, w_uvh, w_uvl, edata,
      s, s_h, s_l, p0h, p0l, (u16*)bufA, (u16*)bufB, flag);

  for (int l=0; l<NLAYER; l++){
    u16* vih = (l & 1) ? p1h : p0h;
    u16* vil = (l & 1) ? p1l : p0l;
    u16* voh = (l & 1) ? p0h : p1h;
    u16* vol = (l & 1) ? p0l : p1l;
    // ---- message block ----
    k_msg<<<N_NODES/16, 256, 0, stream>>>(
        s_h, s_l,
        w_mw1h + (size_t)l*F*F,  w_mw1l + (size_t)l*F*F,
        w_mw2h + (size_t)l*F*F3, w_mw2l + (size_t)l*F*F3,
        c_mb1 + (size_t)l*F, c_mb2 + (size_t)l*F3,
        (u16*)bufA, (u16*)bufB);
    k_agg<<<N_NODES/2, 256, 0, stream>>>(
        edata, bufA, bufB, c_rwp2 + (size_t)l*11*F3,
        vih, vil, voh, vol, s, s_h, s_l);
    // ---- update block ----
    k_uvdot<<<dim3(2, N_NODES/32), 256, 0, stream>>>(
        voh, vol, w_uvh + (size_t)l*256*F, w_uvl + (size_t)l*256*F,
        s, uvFb, dotb, ai_h, ai_l);
    k_upd<<<N_NODES/16, 256, 0, stream>>>(
        ai_h, ai_l,
        w_w1h + (size_t)l*F*256, w_w1l + (size_t)l*F*256,
        w_w2h + (size_t)l*F*F3,  w_w2l + (size_t)l*F*F3,
        c_b1 + (size_t)l*F, c_b2 + (size_t)l*F3,
        dotb, uvFb, s, s_h, s_l, voh, vol,
        (u16*)bufA, (u16*)bufB,
        (l == NLAYER-1) ? (float*)d_out : nullptr);
  }
}